// Round 30
// baseline (151.755 us; speedup 1.0000x reference)
//
#include <hip/hip_runtime.h>

#define HW 128

typedef __attribute__((ext_vector_type(8))) short  bfrag;   // 8 bf16
typedef __attribute__((ext_vector_type(16))) float f16x;    // 32x32 accumulator
typedef __attribute__((ext_vector_type(4)))  float f4;

__device__ __forceinline__ float lrelu(float x) { return x > 0.f ? x : 0.1f * x; }

// RNE fp32 -> bf16
__device__ __forceinline__ short f2bf(float f) {
    unsigned u = __builtin_bit_cast(unsigned, f);
    u = u + 0x7FFFu + ((u >> 16) & 1u);
    return (short)(u >> 16);
}
__device__ __forceinline__ unsigned rne_u(float f) {
    unsigned u = __builtin_bit_cast(unsigned, f);
    return u + 0x7FFFu + ((u >> 16) & 1u);
}

__device__ float g_ktab[32 * 768];                // [b][c][12] att-folded taps
__device__ short g_whi[4096];                     // conv_w bf16 (RNE), [o*64+c]
__device__ short g_y[32 * 128 * 128 * 64];        // y bf16, [b][gy][px][c]  (67 MB)

// ---------- prep: b<32 -> att-folded kernels; b==32 -> W bf16 ----------
__global__ __launch_bounds__(64) void dgfem_prep(
    const float* __restrict__ v, const float* __restrict__ ca_w1,
    const float* __restrict__ ca_w2, const float* __restrict__ k_w1,
    const float* __restrict__ k_w2, const float* __restrict__ conv_w)
{
    const int b = blockIdx.x;
    const int t = threadIdx.x;           // 64 threads

    if (b == 32) {
        for (int i = t; i < 4096; i += 64) g_whi[i] = f2bf(conv_w[i]);
        return;
    }

    __shared__ float vb[64], t1[8], att[64], t2[64];
    vb[t] = v[b * 64 + t];
    __syncthreads();

    if (t < 8) {
        float s = 0.f;
        for (int j = 0; j < 64; ++j) s += vb[j] * ca_w1[t * 64 + j];
        t1[t] = lrelu(s);
    }
    {
        float s = 0.f;
        for (int j = 0; j < 64; ++j) s += vb[j] * k_w1[t * 64 + j];
        t2[t] = lrelu(s);
    }
    __syncthreads();
    {
        float s = 0.f;
        for (int i = 0; i < 8; ++i) s += t1[i] * ca_w2[t * 8 + i];
        att[t] = 1.f / (1.f + expf(-s));
    }
    __syncthreads();
    // fold att[c] into kernel; plain [c][12] layout
    for (int r = t; r < 576; r += 64) {
        int c = r / 9, tp = r - c * 9;
        float s = 0.f;
        for (int j = 0; j < 64; ++j) s += t2[j] * k_w2[r * 64 + j];
        g_ktab[b * 768 + c * 12 + tp] = s * att[c];
    }
}

// ---- pass 1: depthwise 3x3 + lrelu -> y bf16 [b][gy][px][c] (pure streaming) ----
__global__ __launch_bounds__(256) void dgfem_dw(const float* __restrict__ x0)
{
    const int t   = threadIdx.x;          // 32 px-groups x 8 channel-groups
    const int pxg = t & 31, cg = t >> 5;
    const int px0 = pxg << 2;

    // XCD swizzle (4096 % 8 == 0, bijective) — IDENTICAL in pass 2
    const int bid  = blockIdx.x;
    const int orig = (bid & 7) * 512 + (bid >> 3);
    const int b    = orig >> 7;           // 0..31
    const int gy   = orig & 127;          // output row

    __shared__ float kls[768];
    {
        const float* ksrc = g_ktab + b * 768;
        const float rm0 = (gy > 0)   ? 1.f : 0.f;
        const float rm2 = (gy < 127) ? 1.f : 0.f;
        for (int i = t; i < 768; i += 256) {
            int tp = i % 12;
            float val = (tp < 9) ? ksrc[i] : 0.f;
            float rm = (tp < 3) ? rm0 : ((tp < 6) ? 1.f : rm2);
            kls[i] = val * rm;
        }
    }
    __syncthreads();

    const float mL = (pxg > 0)  ? 1.f : 0.f;
    const float mR = (pxg < 31) ? 1.f : 0.f;
    const int   dL = (pxg > 0)  ? -4 : 0;
    const int   dR = (pxg < 31) ? 16 : 12;
    const int r0 = max(gy - 1, 0), r1 = gy, r2 = min(gy + 1, 127);
    const int rowoff0 = r0 * 512 + px0 * 4;
    const int rowoff1 = r1 * 512 + px0 * 4;
    const int rowoff2 = r2 * 512 + px0 * 4;

    const char* xbu = (const char*)x0 + ((size_t)b << 22);

    unsigned pk[4][4];                    // [px][channel-pair] (fully unrolled: static idx)
    unsigned tm[4];

    #pragma unroll
    for (int j = 0; j < 8; ++j) {
        const int c = cg * 8 + j;
        const float* kbp = kls + c * 12;
        f4 kf0 = *(const f4*)(kbp);
        f4 kf1 = *(const f4*)(kbp + 4);
        float k8v = kbp[8];
        const unsigned oC = (unsigned)c << 16;
        float a0 = 0.f, a1 = 0.f, a2 = 0.f, a3 = 0.f;
        #pragma unroll
        for (int r = 0; r < 3; ++r) {
            const unsigned oQ = oC + (unsigned)((r == 0) ? rowoff0 : (r == 1) ? rowoff1 : rowoff2);
            f4    Q = *(const f4*)(xbu + oQ);
            float L = *(const float*)(xbu + oQ + dL);
            float R = *(const float*)(xbu + oQ + dR);
            float k0, k1, k2;
            if (r == 0)      { k0 = kf0.x; k1 = kf0.y; k2 = kf0.z; }
            else if (r == 1) { k0 = kf0.w; k1 = kf1.x; k2 = kf1.y; }
            else             { k0 = kf1.z; k1 = kf1.w; k2 = k8v;   }
            float Lm = L * mL, Rm = R * mR;
            a0 += fmaf(k0, Lm,  fmaf(k1, Q.x, k2 * Q.y));
            a1 += fmaf(k0, Q.x, fmaf(k1, Q.y, k2 * Q.z));
            a2 += fmaf(k0, Q.y, fmaf(k1, Q.z, k2 * Q.w));
            a3 += fmaf(k0, Q.z, fmaf(k1, Q.w, k2 * Rm));
        }
        unsigned u0 = rne_u(lrelu(a0)), u1 = rne_u(lrelu(a1));
        unsigned u2 = rne_u(lrelu(a2)), u3 = rne_u(lrelu(a3));
        if ((j & 1) == 0) {
            tm[0] = u0 >> 16; tm[1] = u1 >> 16; tm[2] = u2 >> 16; tm[3] = u3 >> 16;
        } else {
            const int s = j >> 1;
            pk[0][s] = tm[0] | (u0 & 0xFFFF0000u);
            pk[1][s] = tm[1] | (u1 & 0xFFFF0000u);
            pk[2][s] = tm[2] | (u2 & 0xFFFF0000u);
            pk[3][s] = tm[3] | (u3 & 0xFFFF0000u);
        }
    }

    // store: y[b][gy][px][cg*8 .. +8] — 16B aligned dwordx4 per px
    char* yb = (char*)g_y + (((size_t)(b * 128 + gy) * 128 + px0) * 64 + cg * 8) * 2;
    #pragma unroll
    for (int p = 0; p < 4; ++p) {
        uint4 vv; vv.x = pk[p][0]; vv.y = pk[p][1]; vv.z = pk[p][2]; vv.w = pk[p][3];
        *(uint4*)(yb + p * 128) = vv;
    }
}

// ---- pass 2: 1x1 conv via MFMA, zero LDS, zero barriers (pure streaming) ----
__global__ __launch_bounds__(256) void dgfem_mm(
    const float* __restrict__ conv_b, float* __restrict__ out)
{
    const int t  = threadIdx.x;
    const int w  = t >> 6, l = t & 63;
    const int g  = l >> 5, ln = l & 31;
    const int px = w * 32 + ln;

    // IDENTICAL swizzle to pass 1 -> same (b,gy) on same XCD -> y L2-local
    const int bid  = blockIdx.x;
    const int orig = (bid & 7) * 512 + (bid >> 3);
    const int b    = orig >> 7;
    const int gy   = orig & 127;

    const char* yrow  = (const char*)g_y + ((size_t)(b * 128 + gy) * 128) * 128;
    const char* yfrag = yrow + px * 128 + g * 16;
    const char* wbase = (const char*)g_whi + ln * 128 + g * 16;

    f16x acc0, acc1;
    #pragma unroll
    for (int i = 0; i < 16; ++i) { acc0[i] = 0.f; acc1[i] = 0.f; }

    #pragma unroll
    for (int m = 0; m < 4; ++m) {
        bfrag yh = *(const bfrag*)(yfrag + m * 32);
        bfrag w0 = *(const bfrag*)(wbase + m * 32);
        bfrag w1 = *(const bfrag*)(wbase + m * 32 + 4096);
        acc0 = __builtin_amdgcn_mfma_f32_32x32x16_bf16(w0, yh, acc0, 0, 0, 0);
        acc1 = __builtin_amdgcn_mfma_f32_32x32x16_bf16(w1, yh, acc1, 0, 0, 0);
    }

    // epilogue: D layout col=lane&31, row=(reg&3)+8*(reg>>2)+4*(lane>>5)  [verified 13x]
    float* ob = out + ((size_t)b << 20) + (size_t)gy * HW + px;
    #pragma unroll
    for (int q = 0; q < 4; ++q) {
        const int obase = 8 * q + 4 * g;
        float4 bv0 = *(const float4*)&conv_b[obase];
        float4 bv1 = *(const float4*)&conv_b[32 + obase];
        const float* b0f = (const float*)&bv0;
        const float* b1f = (const float*)&bv1;
        #pragma unroll
        for (int r2 = 0; r2 < 4; ++r2) {
            ob[(size_t)(obase + r2) * 16384]      = acc0[q * 4 + r2] + b0f[r2];
            ob[(size_t)(32 + obase + r2) * 16384] = acc1[q * 4 + r2] + b1f[r2];
        }
    }
}

extern "C" void kernel_launch(void* const* d_in, const int* in_sizes, int n_in,
                              void* d_out, int out_size, void* d_ws, size_t ws_size,
                              hipStream_t stream) {
    const float* x0     = (const float*)d_in[0];
    const float* v      = (const float*)d_in[1];
    const float* ca_w1  = (const float*)d_in[2];
    const float* ca_w2  = (const float*)d_in[3];
    const float* k_w1   = (const float*)d_in[4];
    const float* k_w2   = (const float*)d_in[5];
    const float* conv_w = (const float*)d_in[6];
    const float* conv_b = (const float*)d_in[7];
    float* outp = (float*)d_out;

    dgfem_prep<<<dim3(33), dim3(64), 0, stream>>>(v, ca_w1, ca_w2, k_w1, k_w2, conv_w);
    dgfem_dw<<<dim3(4096), dim3(256), 0, stream>>>(x0);
    dgfem_mm<<<dim3(4096), dim3(256), 0, stream>>>(conv_b, outp);
}

// Round 31
// 77.499 us; speedup vs baseline: 1.9582x; 1.9582x over previous
//
#include <hip/hip_runtime.h>

#define HW 128
#define XBb 16           // byte offset of x double-buffer (16B pad before)
#define XBf 4            // same, in floats
#define KTb 24592        // byte offset of SoA ktab = 16 + 2*12288
#define LDS_BYTES 26896  // 24592 + 2304 (kf0 1024 | kf1 1024 | k8 256)

typedef __attribute__((ext_vector_type(8))) short  bfrag;   // 8 bf16
typedef __attribute__((ext_vector_type(16))) float f16x;    // 32x32 accumulator
typedef __attribute__((ext_vector_type(4)))  float f4;

__device__ __forceinline__ float lrelu(float x) { return x > 0.f ? x : 0.1f * x; }

// RNE fp32 -> bf16
__device__ __forceinline__ short f2bf(float f) {
    unsigned u = __builtin_bit_cast(unsigned, f);
    u = u + 0x7FFFu + ((u >> 16) & 1u);
    return (short)(u >> 16);
}

// SoA per batch: [0..255] kf0 (row*4+tp0..3) | [256..511] kf1 (tp4..7) | [512..575] k8
__device__ float g_ktab[32 * 768];
__device__ short g_whi[4096];                     // conv_w bf16 (RNE), [o*64+c]

// ---------- prep: b<32 -> att-folded kernels (SoA); b==32 -> W bf16 ----------
__global__ __launch_bounds__(64) void dgfem_prep(
    const float* __restrict__ v, const float* __restrict__ ca_w1,
    const float* __restrict__ ca_w2, const float* __restrict__ k_w1,
    const float* __restrict__ k_w2, const float* __restrict__ conv_w)
{
    const int b = blockIdx.x;
    const int t = threadIdx.x;           // 64 threads

    if (b == 32) {
        for (int i = t; i < 4096; i += 64) g_whi[i] = f2bf(conv_w[i]);
        return;
    }

    __shared__ float vb[64], t1[8], att[64], t2[64];
    vb[t] = v[b * 64 + t];
    __syncthreads();

    if (t < 8) {
        float s = 0.f;
        for (int j = 0; j < 64; ++j) s += vb[j] * ca_w1[t * 64 + j];
        t1[t] = lrelu(s);
    }
    {
        float s = 0.f;
        for (int j = 0; j < 64; ++j) s += vb[j] * k_w1[t * 64 + j];
        t2[t] = lrelu(s);
    }
    __syncthreads();
    {
        float s = 0.f;
        for (int i = 0; i < 8; ++i) s += t1[i] * ca_w2[t * 8 + i];
        att[t] = 1.f / (1.f + expf(-s));
    }
    __syncthreads();
    // fold att[c]; SoA layout, row = ((m*2+a)*2+g)*4+j2, c = m*16+g*8+a*4+j2
    for (int r = t; r < 576; r += 64) {
        int c = r / 9, tp = r - c * 9;
        float s = 0.f;
        for (int j = 0; j < 64; ++j) s += t2[j] * k_w2[r * 64 + j];
        int m = c >> 4, g = (c >> 3) & 1, a = (c >> 2) & 1, j2 = c & 3;
        int row = ((m * 2 + a) * 2 + g) * 4 + j2;
        int dst = (tp < 4) ? (row * 4 + tp)
                : (tp < 8) ? (256 + row * 4 + (tp - 4))
                           : (512 + row);
        g_ktab[b * 768 + dst] = s * att[c];
    }
}

__global__ __launch_bounds__(256) void dgfem_main(
    const float* __restrict__ x0, const float* __restrict__ conv_b,
    float* __restrict__ out)
{
    const int t  = threadIdx.x;          // 256 threads = 4 waves
    const int w  = t >> 6;
    const int l  = t & 63;
    const int g  = l >> 5;               // k-half
    const int ln = l & 31;
    const int px = w * 32 + ln;

    // XCD swizzle (4096 % 8 == 0, bijective)
    const int bid  = blockIdx.x;
    const int orig = (bid & 7) * 512 + (bid >> 3);
    const int b    = orig >> 7;          // 0..31
    const int gy   = orig & 127;         // output row

    __shared__ __align__(16) char lds[LDS_BYTES];
    float* ldsf = (float*)lds;

    // stage SoA ktab with row masks folded in (masked row taps -> 0)
    {
        const float* ksrc = g_ktab + b * 768;
        const float rm0 = (gy > 0)   ? 1.f : 0.f;
        const float rm2 = (gy < 127) ? 1.f : 0.f;
        for (int i = t; i < 576; i += 256) {
            float rm;
            if (i < 256)      rm = ((i & 3) < 3) ? rm0 : 1.f;   // taps 0-2 top, 3 center
            else if (i < 512) rm = ((i & 3) < 2) ? 1.f : rm2;   // taps 4-5 center, 6-7 bottom
            else              rm = rm2;                          // tap 8 bottom
            *(float*)(lds + KTb + i * 4) = ksrc[i] * rm;
        }
    }

    // per-lane clamped source offsets: 3 sweeps of 1 KB per wave cover 12 KB/round
    // slot = gs*4+j2s (1536 B each = 3 row-slots), channel = base + gs*8 + j2s
    const int doff = w * 1024 + l * 16;  // this lane's dst offset pattern base
    int inv0, inv1, inv2;
    {
        #pragma unroll
        for (int q = 0; q < 3; ++q) {
            int F      = q * 4096 + doff;
            int slot   = F / 1536;
            int within = F - slot * 1536;
            int rowq   = gy - 1 + (within >> 9);
            int crow   = min(max(rowq, 0), 127);
            int gs = slot >> 2, j2s = slot & 3;
            int iv = (gs * 8 + j2s) * 65536 + crow * 512 + (within & 511);
            if (q == 0) inv0 = iv; else if (q == 1) inv1 = iv; else inv2 = iv;
        }
    }

    const char* xb = (const char*)x0 + ((size_t)b << 22);

    // stage 8 channels (c = m*16 + gs*8 + a*4 + j2s) x 3 row-slots, dbl-buffered
    #define STAGE(rr_, sel_)                                                   \
    {                                                                          \
        const char* srcb = xb + ((size_t)(((rr_) >> 1) * 16 + ((rr_) & 1) * 4) << 16); \
        char* dstb = lds + XBb + (sel_) * 12288 + doff;                        \
        __builtin_amdgcn_global_load_lds(                                      \
            (const __attribute__((address_space(1))) unsigned*)(srcb + inv0),  \
            (__attribute__((address_space(3))) unsigned*)(dstb), 16, 0, 0);    \
        __builtin_amdgcn_global_load_lds(                                      \
            (const __attribute__((address_space(1))) unsigned*)(srcb + inv1),  \
            (__attribute__((address_space(3))) unsigned*)(dstb + 4096), 16, 0, 0); \
        __builtin_amdgcn_global_load_lds(                                      \
            (const __attribute__((address_space(1))) unsigned*)(srcb + inv2),  \
            (__attribute__((address_space(3))) unsigned*)(dstb + 8192), 16, 0, 0); \
    }

    f16x acc0, acc1;
    #pragma unroll
    for (int i = 0; i < 16; ++i) { acc0[i] = 0.f; acc1[i] = 0.f; }

    const float mLf = (px > 0)   ? 1.f : 0.f;
    const float mRf = (px < 127) ? 1.f : 0.f;

    bfrag yh;
    bfrag whi0, whi1;                    // W pair for the CURRENT (even,odd) rounds
    const char* const wbase = (const char*)g_whi + ln * 128 + g * 16;

    STAGE(0, 0);
    __syncthreads();

    // Even rounds (a_=0): W pair loads FIRST (retire ahead of the stage queue).
    #define ROUND(rr_, a_, m_, sel_)                                           \
    {                                                                          \
        if (!(a_)) {                                                           \
            whi0 = *(const bfrag*)(wbase + (m_) * 32);                         \
            whi1 = *(const bfrag*)(wbase + (m_) * 32 + 4096);                  \
        }                                                                      \
        if ((rr_) < 7) STAGE((rr_) + 1, (sel_) ^ 1);                           \
        const float* xbase = ldsf + (XBf + (sel_) * 3072 + g * 1536 + px - 1); \
        const int    krowb = ((rr_) * 2 + g) * 4;                              \
        _Pragma("unroll")                                                      \
        for (int j2 = 0; j2 < 4; ++j2) {                                       \
            f4 kA = *(const f4*)(lds + KTb + (krowb + j2) * 16);               \
            f4 kB = *(const f4*)(lds + KTb + 1024 + (krowb + j2) * 16);        \
            float k8v = *(const float*)(lds + KTb + 2048 + (krowb + j2) * 4);  \
            const float* bA = xbase + j2 * 384;                                \
            float xL0 = bA[0]   * mLf, xC0 = bA[1],   xR0 = bA[2]   * mRf;     \
            float xL1 = bA[128] * mLf, xC1 = bA[129], xR1 = bA[130] * mRf;     \
            float xL2 = bA[256] * mLf, xC2 = bA[257], xR2 = bA[258] * mRf;     \
            float aY = fmaf(kA.x, xL0, fmaf(kA.y, xC0, kA.z * xR0))            \
                     + fmaf(kA.w, xL1, fmaf(kB.x, xC1, kB.y * xR1))            \
                     + fmaf(kB.z, xL2, fmaf(kB.w, xC2, k8v  * xR2));           \
            yh[(a_) * 4 + j2] = f2bf(lrelu(aY));                               \
        }                                                                      \
        if (a_) {                                                              \
            acc0 = __builtin_amdgcn_mfma_f32_32x32x16_bf16(whi0, yh, acc0, 0, 0, 0); \
            acc1 = __builtin_amdgcn_mfma_f32_32x32x16_bf16(whi1, yh, acc1, 0, 0, 0); \
        }                                                                      \
        if ((rr_) < 7) __syncthreads();                                        \
    }

    ROUND(0, 0, 0, 0);
    ROUND(1, 1, 0, 1);
    ROUND(2, 0, 1, 0);
    ROUND(3, 1, 1, 1);
    ROUND(4, 0, 2, 0);
    ROUND(5, 1, 2, 1);
    ROUND(6, 0, 3, 0);
    ROUND(7, 1, 3, 1);

    #undef ROUND
    #undef STAGE

    // epilogue: D layout col=lane&31, row=(reg&3)+8*(reg>>2)+4*(lane>>5)  [verified 13x]
    float* ob = out + ((size_t)b << 20) + (size_t)gy * HW + px;
    #pragma unroll
    for (int q = 0; q < 4; ++q) {
        const int obase = 8 * q + 4 * g;
        float4 bv0 = *(const float4*)&conv_b[obase];
        float4 bv1 = *(const float4*)&conv_b[32 + obase];
        const float* b0f = (const float*)&bv0;
        const float* b1f = (const float*)&bv1;
        #pragma unroll
        for (int r2 = 0; r2 < 4; ++r2) {
            ob[(size_t)(obase + r2) * 16384]      = acc0[q * 4 + r2] + b0f[r2];
            ob[(size_t)(32 + obase + r2) * 16384] = acc1[q * 4 + r2] + b1f[r2];
        }
    }
}

extern "C" void kernel_launch(void* const* d_in, const int* in_sizes, int n_in,
                              void* d_out, int out_size, void* d_ws, size_t ws_size,
                              hipStream_t stream) {
    const float* x0     = (const float*)d_in[0];
    const float* v      = (const float*)d_in[1];
    const float* ca_w1  = (const float*)d_in[2];
    const float* ca_w2  = (const float*)d_in[3];
    const float* k_w1   = (const float*)d_in[4];
    const float* k_w2   = (const float*)d_in[5];
    const float* conv_w = (const float*)d_in[6];
    const float* conv_b = (const float*)d_in[7];
    float* outp = (float*)d_out;

    dgfem_prep<<<dim3(33), dim3(64), 0, stream>>>(v, ca_w1, ca_w2, k_w1, k_w2, conv_w);
    dgfem_main<<<dim3(4096), dim3(256), 0, stream>>>(x0, conv_b, outp);
}